// Round 9
// baseline (204.899 us; speedup 1.0000x reference)
//
#include <hip/hip_runtime.h>
#include <hip/hip_bf16.h>

// Problem constants
constexpr int CB = 2;     // batch
constexpr int CH = 128;   // H
constexpr int CW = 128;   // W
constexpr int CM = 8;     // heads

typedef __bf16 bf16x8 __attribute__((ext_vector_type(8)));
typedef float  f32x4  __attribute__((ext_vector_type(4)));
typedef unsigned short us8 __attribute__((ext_vector_type(8)));
typedef unsigned short us4 __attribute__((ext_vector_type(4)));

__device__ __forceinline__ unsigned short f2bf(float f) {
  __hip_bfloat16 h = __float2bfloat16(f);
  return *reinterpret_cast<unsigned short*>(&h);
}
__device__ __forceinline__ float bf2f(unsigned short u) {
  union { unsigned int i; float f; } v;
  v.i = ((unsigned int)u) << 16;
  return v.f;
}

// ---------------------------------------------------------------------------
// Prep (parallel): compose WC = Wq@[Wd|Wa] via split-k x4 + shfl reduce;
// transpose-round Wp,Wm; composed bias. 449 blocks.
// ---------------------------------------------------------------------------
__global__ __launch_bounds__(256) void prep_all_kernel(
    const float* __restrict__ Wq, const float* __restrict__ bq,
    const float* __restrict__ Wd, const float* __restrict__ bd,
    const float* __restrict__ Wa, const float* __restrict__ ba,
    const float* __restrict__ Wp, const float* __restrict__ Wm,
    unsigned short* __restrict__ WtDA, unsigned short* __restrict__ WtP,
    unsigned short* __restrict__ WtM, float* __restrict__ bda)
{
  const int blk = blockIdx.x, t = threadIdx.x;
  if (blk < 384) {                       // compose: 24576 outputs x 4 partials
    const int gtid = blk * 256 + t;
    const int idx = gtid >> 2;           // output index
    const int kc  = gtid & 3;            // k-chunk
    const int j = idx >> 7, k = idx & 127;
    const int i0 = kc * 32;
    float s = 0.f;
    if (j < 128) {
#pragma unroll
      for (int i = 0; i < 32; ++i)
        s = fmaf(Wq[k * 128 + i0 + i], Wd[(i0 + i) * 128 + j], s);
    } else {
#pragma unroll
      for (int i = 0; i < 32; ++i)
        s = fmaf(Wq[k * 128 + i0 + i], Wa[(i0 + i) * 64 + (j - 128)], s);
    }
    s += __shfl_xor(s, 1);
    s += __shfl_xor(s, 2);
    if (kc == 0) WtDA[j * 128 + k] = f2bf(s);
  } else if (blk < 448) {                // transpose-round Wp, Wm (2 each)
    int idx = (blk - 384) * 256 + t;     // 0..16383
    {
      const int k = idx >> 7, j = idx & 127;
      WtP[j * 128 + k] = f2bf(Wp[idx]);
    }
    {
      const int k = idx >> 7, j = idx & 127;
      WtM[j * 128 + k] = f2bf(Wm[idx]);
    }
  } else {                               // composed bias (192)
    if (t < 192) {
      const int j = t;
      float s = (j < 128) ? bd[j] : ba[j - 128];
      if (j < 128) {
#pragma unroll 8
        for (int i = 0; i < 128; ++i) s = fmaf(bq[i], Wd[i * 128 + j], s);
      } else {
#pragma unroll 8
        for (int i = 0; i < 128; ++i) s = fmaf(bq[i], Wa[i * 64 + (j - 128)], s);
      }
      bda[j] = s;
    }
  }
}

// ---------------------------------------------------------------------------
// LDS helpers: 16B-slot XOR swizzle (write and read sides identical).
// ---------------------------------------------------------------------------
__device__ __forceinline__ void stage_B(const unsigned short* __restrict__ src,
                                        unsigned short* __restrict__ lds,
                                        int n_us8)
{
  for (int v = threadIdx.x; v < n_us8; v += 256) {
    const us8 d = *(const us8*)(src + v * 8);
    const int col = v >> 4;
    const int slot = (v & 15) ^ (col & 7);
    *(us8*)(lds + col * 128 + slot * 8) = d;
  }
}
__device__ __forceinline__ bf16x8 lds_frag(const unsigned short* __restrict__ lds,
                                           int rc, int ko)
{
  const int slot = (ko >> 3) ^ (rc & 7);
  return *(const bf16x8*)(lds + rc * 128 + slot * 8);
}

// ---------------------------------------------------------------------------
// Fused pre-sample GEMM, LDS-staged both operands, column-split blocks.
// (unchanged from R7 — verified correct at absmax 2.44e-4)
// ---------------------------------------------------------------------------
__global__ __launch_bounds__(256) void pre_gemm_kernel(
    const float* __restrict__ z_q, const float* __restrict__ x0,
    const float* __restrict__ x1,
    const unsigned short* __restrict__ WtDA, const float* __restrict__ bda,
    const unsigned short* __restrict__ WtP,  const float* __restrict__ bp,
    float* __restrict__ dl2, float* __restrict__ Alog,
    unsigned short* __restrict__ Wx, int nZv)
{
  __shared__ __align__(16) unsigned short smem[24576];

  const int t  = threadIdx.x;
  const int w  = t >> 6;
  const int l  = t & 63;
  const int lr = l & 15;
  const int kg = l >> 4;
  const int blk = blockIdx.x;

  if (blk < nZv) {
    unsigned short* Bsh = smem;            // 96 cols x 128
    unsigned short* Ahi = smem + 12288;    // 64 rows x 128
    const int r0 = (blk >> 1) * 64;
    const int cg = blk & 1;

    stage_B(WtDA + cg * 96 * 128, Bsh, 1536);
    {
      const float4* Ag = (const float4*)(z_q + (size_t)r0 * 128);
#pragma unroll
      for (int i = 0; i < 8; ++i) {
        const int v = t + i * 256;
        const float4 f = Ag[v];
        const int flat = v * 4;
        const int row = flat >> 7;
        const int ko  = flat & 127;
        us4 h;
        h[0] = f2bf(f.x); h[1] = f2bf(f.y); h[2] = f2bf(f.z); h[3] = f2bf(f.w);
        *(us4*)(Ahi + row * 128 + (((ko >> 3) ^ (row & 7)) << 3) + (ko & 7)) = h;
      }
    }
    __syncthreads();

    f32x4 acc[6];
#pragma unroll
    for (int jt = 0; jt < 6; ++jt) acc[jt] = (f32x4){0.f, 0.f, 0.f, 0.f};

    const int lrow = w * 16 + lr;
#pragma unroll
    for (int k0 = 0; k0 < 128; k0 += 32) {
      const int ko = k0 + kg * 8;
      const bf16x8 ah = lds_frag(Ahi, lrow, ko);
#pragma unroll
      for (int jt = 0; jt < 6; ++jt) {
        const bf16x8 bh = lds_frag(Bsh, jt * 16 + lr, ko);
        acc[jt] = __builtin_amdgcn_mfma_f32_16x16x32_bf16(ah, bh, acc[jt], 0, 0, 0);
      }
    }

    const int scol = ((lr >> 1) & 3) * 32 + ((lr >> 3) & 1) * 2 + (lr & 1);
#pragma unroll
    for (int jt = 0; jt < 6; ++jt) {
      const int jtg = cg * 6 + jt;
      if (jtg < 8) {
        const float bv = bda[jtg * 16 + lr];
#pragma unroll
        for (int ri = 0; ri < 4; ++ri) {
          const int row = r0 + w * 16 + kg * 4 + ri;
          dl2[(size_t)row * 128 + jtg * 4 + scol] = acc[jt][ri] + bv;
        }
      } else {
        const int col = (jtg - 8) * 16 + lr;
        const float bv = bda[128 + col];
#pragma unroll
        for (int ri = 0; ri < 4; ++ri) {
          const int row = r0 + w * 16 + kg * 4 + ri;
          Alog[(size_t)row * 64 + col] = acc[jt][ri] + bv;
        }
      }
    }
  } else {
    unsigned short* Bsh = smem;            // 64 cols x 128
    unsigned short* Ahi = smem + 8192;
    unsigned short* Alo = smem + 16384;
    const int i = blk - nZv;
    const int r0 = (i >> 1) * 64;
    const int cg = i & 1;
    const float* A = (r0 < 8192) ? (x0 + (size_t)r0 * 128)
                                 : (x1 + (size_t)(r0 - 8192) * 128);

    stage_B(WtP + cg * 64 * 128, Bsh, 1024);
    {
      const float4* Ag = (const float4*)A;
#pragma unroll
      for (int ii = 0; ii < 8; ++ii) {
        const int v = t + ii * 256;
        const float4 f = Ag[v];
        const int flat = v * 4;
        const int row = flat >> 7;
        const int ko  = flat & 127;
        const float ff[4] = {f.x, f.y, f.z, f.w};
        us4 h, lo;
#pragma unroll
        for (int u = 0; u < 4; ++u) {
          h[u]  = f2bf(ff[u]);
          lo[u] = f2bf(ff[u] - bf2f(h[u]));
        }
        const int off = row * 128 + (((ko >> 3) ^ (row & 7)) << 3) + (ko & 7);
        *(us4*)(Ahi + off) = h;
        *(us4*)(Alo + off) = lo;
      }
    }
    __syncthreads();

    f32x4 acc[4];
#pragma unroll
    for (int jt = 0; jt < 4; ++jt) acc[jt] = (f32x4){0.f, 0.f, 0.f, 0.f};

    const int lrow = w * 16 + lr;
#pragma unroll
    for (int k0 = 0; k0 < 128; k0 += 32) {
      const int ko = k0 + kg * 8;
      const bf16x8 ah = lds_frag(Ahi, lrow, ko);
      const bf16x8 al = lds_frag(Alo, lrow, ko);
#pragma unroll
      for (int jt = 0; jt < 4; ++jt) {
        const bf16x8 bh = lds_frag(Bsh, jt * 16 + lr, ko);
        acc[jt] = __builtin_amdgcn_mfma_f32_16x16x32_bf16(ah, bh, acc[jt], 0, 0, 0);
        acc[jt] = __builtin_amdgcn_mfma_f32_16x16x32_bf16(al, bh, acc[jt], 0, 0, 0);
      }
    }

#pragma unroll
    for (int jt = 0; jt < 4; ++jt) {
      const int col = cg * 64 + jt * 16 + lr;
      const float bv = bp[col];
#pragma unroll
      for (int ri = 0; ri < 4; ++ri) {
        const int row = r0 + w * 16 + kg * 4 + ri;
        Wx[(size_t)row * 128 + col] = f2bf(acc[jt][ri] + bv);
      }
    }
  }
}

// ---------------------------------------------------------------------------
// Final GEMM (unchanged from R7)
// ---------------------------------------------------------------------------
__global__ __launch_bounds__(256) void final_gemm_kernel(
    const unsigned short* __restrict__ Pbf,
    const unsigned short* __restrict__ WtM,
    const float* __restrict__ bm, float* __restrict__ out)
{
  __shared__ __align__(16) unsigned short smem[16384];
  unsigned short* Bsh = smem;
  unsigned short* Ash = smem + 8192;

  const int t  = threadIdx.x;
  const int w  = t >> 6;
  const int l  = t & 63;
  const int lr = l & 15;
  const int kg = l >> 4;
  const int r0 = (blockIdx.x >> 1) * 64;
  const int cg = blockIdx.x & 1;

  stage_B(WtM + cg * 64 * 128, Bsh, 1024);
  stage_B(Pbf + (size_t)r0 * 128, Ash, 1024);
  __syncthreads();

  f32x4 acc[4];
#pragma unroll
  for (int jt = 0; jt < 4; ++jt) acc[jt] = (f32x4){0.f, 0.f, 0.f, 0.f};

  const int lrow = w * 16 + lr;
#pragma unroll
  for (int k0 = 0; k0 < 128; k0 += 32) {
    const int ko = k0 + kg * 8;
    const bf16x8 av = lds_frag(Ash, lrow, ko);
#pragma unroll
    for (int jt = 0; jt < 4; ++jt) {
      const bf16x8 bh = lds_frag(Bsh, jt * 16 + lr, ko);
      acc[jt] = __builtin_amdgcn_mfma_f32_16x16x32_bf16(av, bh, acc[jt], 0, 0, 0);
    }
  }

#pragma unroll
  for (int jt = 0; jt < 4; ++jt) {
    const int col = cg * 64 + jt * 16 + lr;
    const float bv = bm[col];
#pragma unroll
    for (int ri = 0; ri < 4; ++ri) {
      const int row = r0 + w * 16 + kg * 4 + ri;
      out[(size_t)row * 128 + col] = acc[jt][ri] + bv;
    }
  }
}

// ---------------------------------------------------------------------------
// Sample kernel v2: 64 threads per query (c2-packing).
// Thread (m, c2) with c2=(yp_off<<1)|lp computes BOTH half outputs:
//   - 4 corners x 32B (two adjacent us8 loads) -> 8 gathers in flight (2x MLP)
//   - softmax + dl2/p_q/address calc computed once per TWO outputs
//   - pair of bf16 outputs packed into one 4B coalesced store
// 256-thread blocks = 4 queries; XCD chunking: queries [xcd*4096, +4096).
// Scramble identical to R7: k'=h>>5; x'=(w>>5)+(h&31)*4; y'=(c>>2)+(w&31)*4;
// l'=(c>>1)&1; cv'=s+8*(c&1); p_q batch = m&1.  c = c2*2 + half.
// ---------------------------------------------------------------------------
__global__ __launch_bounds__(256) void sample_attn_kernel(
    const float* __restrict__ Alog,          // [B*H*W, 64]
    const float* __restrict__ dl2,           // [B*H*W][kk][m][lp][2]
    const float* __restrict__ p_q,           // [B, H, W, 2]
    const unsigned short* __restrict__ Wx,   // rows 0..8191 = x0, 8192.. = x1
    unsigned short* __restrict__ Pbf)        // [B*H*W, 128] bf16
{
  const int bid = blockIdx.x;
  const int t  = threadIdx.x;
  const int qi = t >> 6;
  const int l  = t & 63;
  const int m  = l >> 3;
  const int c2 = l & 7;
  const int ypo = c2 >> 1;
  const int lp  = c2 & 1;

  const int q = (bid & 7) * 4096 + (bid >> 3) * 4 + qi;
  const int w = q & (CW - 1);
  const int h = (q >> 7) & (CH - 1);
  const int b = q >> 14;

  const int kk = h >> 5;
  const int xp = (w >> 5) + ((h & 31) << 2);
  const int yp = ypo + ((w & 31) << 2);

  // --- independent scalar loads first ---
  const size_t qp = ((size_t)b * CH + yp) * CW + xp;
  const float2 dxy = *(const float2*)(dl2 + qp * 128 + kk * 32 + m * 4 + lp * 2);

  const int pb = m & 1;                    // (b*8+m)%2, faithful quirk
  const float2 pq2 = *(const float2*)(p_q + ((((size_t)pb * CH + yp) * CW + xp) * 2));

  const float* al = Alog + (size_t)q * 64 + m * 8;
  const float4 al0 = ((const float4*)al)[0];
  const float4 al1 = ((const float4*)al)[1];

  const int wl = lp ? 128 : 64;
  const int hl = wl;
  const int imgbase = lp ? (8192 + b * 16384) : (b * 4096);

  // grid_sample coords (align_corners=False, zeros padding), faithful math
  const float fwl1 = (float)(wl - 1);
  const float cx = pq2.x * fwl1 + dxy.x;
  const float cy = pq2.y * fwl1 + dxy.y;
  const float gx = 2.f * cx / fwl1 - 1.f;
  const float gy = 2.f * cy / fwl1 - 1.f;
  const float ix = ((gx + 1.f) * (float)wl - 1.f) * 0.5f;
  const float iy = ((gy + 1.f) * (float)hl - 1.f) * 0.5f;
  const float x0f = floorf(ix), y0f = floorf(iy);
  const float fx1 = ix - x0f, fy1 = iy - y0f;
  const float fx0 = 1.f - fx1, fy0 = 1.f - fy1;
  const int xi = (int)x0f, yi = (int)y0f;

  const float vx0 = ((unsigned)xi < (unsigned)wl) ? 1.f : 0.f;
  const float vx1 = ((unsigned)(xi + 1) < (unsigned)wl) ? 1.f : 0.f;
  const float vy0 = ((unsigned)yi < (unsigned)hl) ? 1.f : 0.f;
  const float vy1 = ((unsigned)(yi + 1) < (unsigned)hl) ? 1.f : 0.f;
  const int xc0 = min(max(xi, 0), wl - 1);
  const int xc1 = min(max(xi + 1, 0), wl - 1);
  const int yc0 = min(max(yi, 0), hl - 1);
  const int yc1 = min(max(yi + 1, 0), hl - 1);

  // --- 8 independent 16B gathers (4 corners x 2 halves), one clause ---
  const unsigned short* base = Wx + (size_t)imgbase * 128 + m * 16;
  const unsigned short* p00 = base + (size_t)(yc0 * wl + xc0) * 128;
  const unsigned short* p01 = base + (size_t)(yc0 * wl + xc1) * 128;
  const unsigned short* p10 = base + (size_t)(yc1 * wl + xc0) * 128;
  const unsigned short* p11 = base + (size_t)(yc1 * wl + xc1) * 128;

  const us8 a00 = *(const us8*)p00, b00 = *(const us8*)(p00 + 8);
  const us8 a01 = *(const us8*)p01, b01 = *(const us8*)(p01 + 8);
  const us8 a10 = *(const us8*)p10, b10 = *(const us8*)(p10 + 8);
  const us8 a11 = *(const us8*)p11, b11 = *(const us8*)(p11 + 8);

  // --- softmax (overlaps gather latency) ---
  float lg[8] = {al0.x, al0.y, al0.z, al0.w, al1.x, al1.y, al1.z, al1.w};
  float mx = -3.0e38f;
#pragma unroll
  for (int s = 0; s < 8; ++s) mx = fmaxf(mx, lg[s]);
  float se = 0.f;
#pragma unroll
  for (int s = 0; s < 8; ++s) { lg[s] = __expf(lg[s] - mx); se += lg[s]; }
  const float inv = 1.f / se;

  const float w00 = fy0 * fx0 * vy0 * vx0;
  const float w01 = fy0 * fx1 * vy0 * vx1;
  const float w10 = fy1 * fx0 * vy1 * vx0;
  const float w11 = fy1 * fx1 * vy1 * vx1;

  float o0 = 0.f, o1 = 0.f;
#pragma unroll
  for (int s = 0; s < 8; ++s) {
    const float ws = lg[s] * inv;
    float v0 = w00 * bf2f(a00[s]);
    v0 = fmaf(w01, bf2f(a01[s]), v0);
    v0 = fmaf(w10, bf2f(a10[s]), v0);
    v0 = fmaf(w11, bf2f(a11[s]), v0);
    o0 = fmaf(ws, v0, o0);
    float v1 = w00 * bf2f(b00[s]);
    v1 = fmaf(w01, bf2f(b01[s]), v1);
    v1 = fmaf(w10, bf2f(b10[s]), v1);
    v1 = fmaf(w11, bf2f(b11[s]), v1);
    o1 = fmaf(ws, v1, o1);
  }

  // pack the two bf16 outputs (cols m*16+c2*2 and +1) into one 4B store
  const unsigned int packed =
      (unsigned int)f2bf(o0) | ((unsigned int)f2bf(o1) << 16);
  *(unsigned int*)(Pbf + (size_t)q * 128 + m * 16 + c2 * 2) = packed;
}

// ---------------------------------------------------------------------------
extern "C" void kernel_launch(void* const* d_in, const int* in_sizes, int n_in,
                              void* d_out, int out_size, void* d_ws, size_t ws_size,
                              hipStream_t stream)
{
  const float* z_q = (const float*)d_in[0];
  const float* x0  = (const float*)d_in[1];
  const float* x1  = (const float*)d_in[2];
  const float* p_q = (const float*)d_in[3];
  const float* Wq  = (const float*)d_in[4];
  const float* bq  = (const float*)d_in[5];
  const float* Wd  = (const float*)d_in[6];
  const float* bd  = (const float*)d_in[7];
  const float* Wa  = (const float*)d_in[8];
  const float* ba  = (const float*)d_in[9];
  const float* Wp  = (const float*)d_in[10];
  const float* bp  = (const float*)d_in[11];
  const float* Wm  = (const float*)d_in[12];
  const float* bm  = (const float*)d_in[13];

  float* ws = (float*)d_ws;
  const int NQ = CB * CH * CW;   // 32768

  // bf16 weight area (ushorts): WtDA 24576 | WtP 16384 | WtM 16384
  unsigned short* Wts  = (unsigned short*)ws;
  unsigned short* WtDA = Wts;
  unsigned short* WtP  = Wts + 24576;
  unsigned short* WtM  = Wts + 40960;
  float* bda = ws + 28672;                        // 192 composed bias

  float* dl2  = ws + 28864;                       // [NQ,128] fp32 scrambled
  float* Alog = dl2 + 4194304;                    // [NQ,64] fp32
  unsigned short* Wx  = (unsigned short*)(Alog + 2097152);   // [40960,128] bf16
  unsigned short* Pbf = Wx + 5242880;             // [NQ,128] bf16

  prep_all_kernel<<<449, 256, 0, stream>>>(Wq, bq, Wd, bd, Wa, ba, Wp, Wm,
                                           WtDA, WtP, WtM, bda);

  const int nZv = 1024;                           // 512 row-tiles x 2 col-halves
  pre_gemm_kernel<<<nZv + 1280, 256, 0, stream>>>(z_q, x0, x1, WtDA, bda,
                                                  WtP, bp, dl2, Alog, Wx, nZv);

  sample_attn_kernel<<<NQ / 4, 256, 0, stream>>>(Alog, dl2, p_q, Wx, Pbf);

  final_gemm_kernel<<<NQ / 32, 256, 0, stream>>>(Pbf, WtM, bm, (float*)d_out);
}

// Round 10
// 181.565 us; speedup vs baseline: 1.1285x; 1.1285x over previous
//
#include <hip/hip_runtime.h>
#include <hip/hip_bf16.h>

// Problem constants
constexpr int CB = 2;     // batch
constexpr int CH = 128;   // H
constexpr int CW = 128;   // W
constexpr int CM = 8;     // heads

typedef __bf16 bf16x8 __attribute__((ext_vector_type(8)));
typedef float  f32x4  __attribute__((ext_vector_type(4)));
typedef unsigned short us8 __attribute__((ext_vector_type(8)));
typedef unsigned short us4 __attribute__((ext_vector_type(4)));

__device__ __forceinline__ unsigned short f2bf(float f) {
  __hip_bfloat16 h = __float2bfloat16(f);
  return *reinterpret_cast<unsigned short*>(&h);
}
__device__ __forceinline__ float bf2f(unsigned short u) {
  union { unsigned int i; float f; } v;
  v.i = ((unsigned int)u) << 16;
  return v.f;
}

// ---------------------------------------------------------------------------
// Prep (parallel): compose WC = Wq@[Wd|Wa] via split-k x4 + shfl reduce;
// transpose-round Wp,Wm; composed bias. 449 blocks. (unchanged from R7)
// ---------------------------------------------------------------------------
__global__ __launch_bounds__(256) void prep_all_kernel(
    const float* __restrict__ Wq, const float* __restrict__ bq,
    const float* __restrict__ Wd, const float* __restrict__ bd,
    const float* __restrict__ Wa, const float* __restrict__ ba,
    const float* __restrict__ Wp, const float* __restrict__ Wm,
    unsigned short* __restrict__ WtDA, unsigned short* __restrict__ WtP,
    unsigned short* __restrict__ WtM, float* __restrict__ bda)
{
  const int blk = blockIdx.x, t = threadIdx.x;
  if (blk < 384) {                       // compose: 24576 outputs x 4 partials
    const int gtid = blk * 256 + t;
    const int idx = gtid >> 2;           // output index
    const int kc  = gtid & 3;            // k-chunk
    const int j = idx >> 7, k = idx & 127;
    const int i0 = kc * 32;
    float s = 0.f;
    if (j < 128) {
#pragma unroll
      for (int i = 0; i < 32; ++i)
        s = fmaf(Wq[k * 128 + i0 + i], Wd[(i0 + i) * 128 + j], s);
    } else {
#pragma unroll
      for (int i = 0; i < 32; ++i)
        s = fmaf(Wq[k * 128 + i0 + i], Wa[(i0 + i) * 64 + (j - 128)], s);
    }
    s += __shfl_xor(s, 1);
    s += __shfl_xor(s, 2);
    if (kc == 0) WtDA[j * 128 + k] = f2bf(s);
  } else if (blk < 448) {                // transpose-round Wp, Wm
    int idx = (blk - 384) * 256 + t;     // 0..16383
    {
      const int k = idx >> 7, j = idx & 127;
      WtP[j * 128 + k] = f2bf(Wp[idx]);
    }
    {
      const int k = idx >> 7, j = idx & 127;
      WtM[j * 128 + k] = f2bf(Wm[idx]);
    }
  } else {                               // composed bias (192)
    if (t < 192) {
      const int j = t;
      float s = (j < 128) ? bd[j] : ba[j - 128];
      if (j < 128) {
#pragma unroll 8
        for (int i = 0; i < 128; ++i) s = fmaf(bq[i], Wd[i * 128 + j], s);
      } else {
#pragma unroll 8
        for (int i = 0; i < 128; ++i) s = fmaf(bq[i], Wa[i * 64 + (j - 128)], s);
      }
      bda[j] = s;
    }
  }
}

// ---------------------------------------------------------------------------
// LDS helpers: 16B-slot XOR swizzle (write and read sides identical).
// ---------------------------------------------------------------------------
__device__ __forceinline__ void stage_B(const unsigned short* __restrict__ src,
                                        unsigned short* __restrict__ lds,
                                        int n_us8)
{
  for (int v = threadIdx.x; v < n_us8; v += 256) {
    const us8 d = *(const us8*)(src + v * 8);
    const int col = v >> 4;
    const int slot = (v & 15) ^ (col & 7);
    *(us8*)(lds + col * 128 + slot * 8) = d;
  }
}
__device__ __forceinline__ bf16x8 lds_frag(const unsigned short* __restrict__ lds,
                                           int rc, int ko)
{
  const int slot = (ko >> 3) ^ (rc & 7);
  return *(const bf16x8*)(lds + rc * 128 + slot * 8);
}

// ---------------------------------------------------------------------------
// Fused pre-sample GEMM (R7 structure). NEW in epilogue:
//  - dl2 stores the PRE-FOLDED sampling coordinate fmaf(p_q, wl-1, acc+bias)
//    (same fmaf the sample kernel used -> bit-identical), killing the p_q
//    load + address calc in the hot sample kernel. pb=m&1, lp, comp are all
//    static per dl2 column: col = kk*32 + m*4 + lp*2 + comp.
//  - Alog stored as bf16 (one 16B load in sample instead of two).
// ---------------------------------------------------------------------------
__global__ __launch_bounds__(256) void pre_gemm_kernel(
    const float* __restrict__ z_q, const float* __restrict__ x0,
    const float* __restrict__ x1, const float* __restrict__ p_q,
    const unsigned short* __restrict__ WtDA, const float* __restrict__ bda,
    const unsigned short* __restrict__ WtP,  const float* __restrict__ bp,
    float* __restrict__ dl2, unsigned short* __restrict__ AlogBf,
    unsigned short* __restrict__ Wx, int nZv)
{
  __shared__ __align__(16) unsigned short smem[24576];

  const int t  = threadIdx.x;
  const int w  = t >> 6;
  const int l  = t & 63;
  const int lr = l & 15;
  const int kg = l >> 4;
  const int blk = blockIdx.x;

  if (blk < nZv) {
    unsigned short* Bsh = smem;            // 96 cols x 128
    unsigned short* Ahi = smem + 12288;    // 64 rows x 128
    const int r0 = (blk >> 1) * 64;
    const int cg = blk & 1;

    stage_B(WtDA + cg * 96 * 128, Bsh, 1536);
    {
      const float4* Ag = (const float4*)(z_q + (size_t)r0 * 128);
#pragma unroll
      for (int i = 0; i < 8; ++i) {
        const int v = t + i * 256;
        const float4 f = Ag[v];
        const int flat = v * 4;
        const int row = flat >> 7;
        const int ko  = flat & 127;
        us4 h;
        h[0] = f2bf(f.x); h[1] = f2bf(f.y); h[2] = f2bf(f.z); h[3] = f2bf(f.w);
        *(us4*)(Ahi + row * 128 + (((ko >> 3) ^ (row & 7)) << 3) + (ko & 7)) = h;
      }
    }
    __syncthreads();

    f32x4 acc[6];
#pragma unroll
    for (int jt = 0; jt < 6; ++jt) acc[jt] = (f32x4){0.f, 0.f, 0.f, 0.f};

    const int lrow = w * 16 + lr;
#pragma unroll
    for (int k0 = 0; k0 < 128; k0 += 32) {
      const int ko = k0 + kg * 8;
      const bf16x8 ah = lds_frag(Ahi, lrow, ko);
#pragma unroll
      for (int jt = 0; jt < 6; ++jt) {
        const bf16x8 bh = lds_frag(Bsh, jt * 16 + lr, ko);
        acc[jt] = __builtin_amdgcn_mfma_f32_16x16x32_bf16(ah, bh, acc[jt], 0, 0, 0);
      }
    }

    // dl2 column decode from lr: kk=(lr>>1)&3, lp=(lr>>3)&1, comp=lr&1
    const int comp = lr & 1;
    const int lpv  = (lr >> 3) & 1;
    const float fwl1 = lpv ? 127.f : 63.f;
    const int scol = ((lr >> 1) & 3) * 32 + lpv * 2 + comp;

    // hoist p_q values (pb=0/1) per output row; pb = jtg&1 = jt&1 (cg*6 even)
    float pqv[2][4];
#pragma unroll
    for (int ri = 0; ri < 4; ++ri) {
      const int row = r0 + w * 16 + kg * 4 + ri;
      const int ypq = (row >> 7) & 127;
      const int xpq = row & 127;
      pqv[0][ri] = p_q[(((size_t)ypq) * 128 + xpq) * 2 + comp];
      pqv[1][ri] = p_q[(((size_t)(128 + ypq)) * 128 + xpq) * 2 + comp];
    }

#pragma unroll
    for (int jt = 0; jt < 6; ++jt) {
      const int jtg = cg * 6 + jt;
      if (jtg < 8) {
        const float bv = bda[jtg * 16 + lr];
#pragma unroll
        for (int ri = 0; ri < 4; ++ri) {
          const int row = r0 + w * 16 + kg * 4 + ri;
          dl2[(size_t)row * 128 + jtg * 4 + scol] =
              fmaf(pqv[jt & 1][ri], fwl1, acc[jt][ri] + bv);
        }
      } else {
        const int col = (jtg - 8) * 16 + lr;
        const float bv = bda[128 + col];
#pragma unroll
        for (int ri = 0; ri < 4; ++ri) {
          const int row = r0 + w * 16 + kg * 4 + ri;
          AlogBf[(size_t)row * 64 + col] = f2bf(acc[jt][ri] + bv);
        }
      }
    }
  } else {
    unsigned short* Bsh = smem;            // 64 cols x 128
    unsigned short* Ahi = smem + 8192;
    unsigned short* Alo = smem + 16384;
    const int i = blk - nZv;
    const int r0 = (i >> 1) * 64;
    const int cg = i & 1;
    const float* A = (r0 < 8192) ? (x0 + (size_t)r0 * 128)
                                 : (x1 + (size_t)(r0 - 8192) * 128);

    stage_B(WtP + cg * 64 * 128, Bsh, 1024);
    {
      const float4* Ag = (const float4*)A;
#pragma unroll
      for (int ii = 0; ii < 8; ++ii) {
        const int v = t + ii * 256;
        const float4 f = Ag[v];
        const int flat = v * 4;
        const int row = flat >> 7;
        const int ko  = flat & 127;
        const float ff[4] = {f.x, f.y, f.z, f.w};
        us4 h, lo;
#pragma unroll
        for (int u = 0; u < 4; ++u) {
          h[u]  = f2bf(ff[u]);
          lo[u] = f2bf(ff[u] - bf2f(h[u]));
        }
        const int off = row * 128 + (((ko >> 3) ^ (row & 7)) << 3) + (ko & 7);
        *(us4*)(Ahi + off) = h;
        *(us4*)(Alo + off) = lo;
      }
    }
    __syncthreads();

    f32x4 acc[4];
#pragma unroll
    for (int jt = 0; jt < 4; ++jt) acc[jt] = (f32x4){0.f, 0.f, 0.f, 0.f};

    const int lrow = w * 16 + lr;
#pragma unroll
    for (int k0 = 0; k0 < 128; k0 += 32) {
      const int ko = k0 + kg * 8;
      const bf16x8 ah = lds_frag(Ahi, lrow, ko);
      const bf16x8 al = lds_frag(Alo, lrow, ko);
#pragma unroll
      for (int jt = 0; jt < 4; ++jt) {
        const bf16x8 bh = lds_frag(Bsh, jt * 16 + lr, ko);
        acc[jt] = __builtin_amdgcn_mfma_f32_16x16x32_bf16(ah, bh, acc[jt], 0, 0, 0);
        acc[jt] = __builtin_amdgcn_mfma_f32_16x16x32_bf16(al, bh, acc[jt], 0, 0, 0);
      }
    }

#pragma unroll
    for (int jt = 0; jt < 4; ++jt) {
      const int col = cg * 64 + jt * 16 + lr;
      const float bv = bp[col];
#pragma unroll
      for (int ri = 0; ri < 4; ++ri) {
        const int row = r0 + w * 16 + kg * 4 + ri;
        Wx[(size_t)row * 128 + col] = f2bf(acc[jt][ri] + bv);
      }
    }
  }
}

// ---------------------------------------------------------------------------
// Final GEMM (unchanged from R7)
// ---------------------------------------------------------------------------
__global__ __launch_bounds__(256) void final_gemm_kernel(
    const unsigned short* __restrict__ Pbf,
    const unsigned short* __restrict__ WtM,
    const float* __restrict__ bm, float* __restrict__ out)
{
  __shared__ __align__(16) unsigned short smem[16384];
  unsigned short* Bsh = smem;
  unsigned short* Ash = smem + 8192;

  const int t  = threadIdx.x;
  const int w  = t >> 6;
  const int l  = t & 63;
  const int lr = l & 15;
  const int kg = l >> 4;
  const int r0 = (blockIdx.x >> 1) * 64;
  const int cg = blockIdx.x & 1;

  stage_B(WtM + cg * 64 * 128, Bsh, 1024);
  stage_B(Pbf + (size_t)r0 * 128, Ash, 1024);
  __syncthreads();

  f32x4 acc[4];
#pragma unroll
  for (int jt = 0; jt < 4; ++jt) acc[jt] = (f32x4){0.f, 0.f, 0.f, 0.f};

  const int lrow = w * 16 + lr;
#pragma unroll
  for (int k0 = 0; k0 < 128; k0 += 32) {
    const int ko = k0 + kg * 8;
    const bf16x8 av = lds_frag(Ash, lrow, ko);
#pragma unroll
    for (int jt = 0; jt < 4; ++jt) {
      const bf16x8 bh = lds_frag(Bsh, jt * 16 + lr, ko);
      acc[jt] = __builtin_amdgcn_mfma_f32_16x16x32_bf16(av, bh, acc[jt], 0, 0, 0);
    }
  }

#pragma unroll
  for (int jt = 0; jt < 4; ++jt) {
    const int col = cg * 64 + jt * 16 + lr;
    const float bv = bm[col];
#pragma unroll
    for (int ri = 0; ri < 4; ++ri) {
      const int row = r0 + w * 16 + kg * 4 + ri;
      out[(size_t)row * 128 + col] = acc[jt][ri] + bv;
    }
  }
}

// ---------------------------------------------------------------------------
// Sample kernel: R7 structure (1 query per 128-thread block, XCD chunking),
// minus two vmem loads per thread:
//   - dl2 now holds the pre-folded coordinate (p_q fold done in pre_gemm)
//   - logits read as ONE 16B bf16 load
// 6 vmem instructions/thread: dl2 float2, logits us8, 4 corner gathers.
// Scramble: k'=h>>5; x'=(w>>5)+(h&31)*4; y'=(c>>2)+(w&31)*4; l'=(c>>1)&1;
// cv'=s+8*(c&1).
// ---------------------------------------------------------------------------
__global__ __launch_bounds__(128) void sample_attn_kernel(
    const unsigned short* __restrict__ AlogBf,   // [B*H*W, 64] bf16
    const float* __restrict__ dl2,               // [B*H*W][kk][m][lp][2] folded
    const unsigned short* __restrict__ Wx,       // rows 0..8191 x0, 8192.. x1
    unsigned short* __restrict__ Pbf)            // [B*H*W, 128] bf16
{
  const int bid = blockIdx.x;
  const int q = (bid & 7) * 4096 + (bid >> 3);   // XCD chunking (bijective)
  const int w = q & (CW - 1);
  const int h = (q >> 7) & (CH - 1);
  const int b = q >> 14;
  const int t = threadIdx.x;
  const int m = t >> 4;
  const int c = t & 15;

  const int kk   = h >> 5;
  const int xp   = (w >> 5) + ((h & 31) << 2);
  const int yp   = (c >> 2) + ((w & 31) << 2);
  const int lp   = (c >> 1) & 1;
  const int half = c & 1;

  // --- two independent loads: folded coords + bf16 logits ---
  const size_t qp = ((size_t)b * CH + yp) * CW + xp;
  const float2 cxy = *(const float2*)(dl2 + qp * 128 + kk * 32 + m * 4 + lp * 2);
  const us8 alv = *(const us8*)(AlogBf + (size_t)q * 64 + m * 8);

  const int wl = lp ? 128 : 64;
  const int hl = wl;
  const int imgbase = lp ? (8192 + b * 16384) : (b * 4096);

  // grid_sample coords (align_corners=False, zeros padding), faithful math
  const float fwl1 = (float)(wl - 1);
  const float gx = 2.f * cxy.x / fwl1 - 1.f;
  const float gy = 2.f * cxy.y / fwl1 - 1.f;
  const float ix = ((gx + 1.f) * (float)wl - 1.f) * 0.5f;
  const float iy = ((gy + 1.f) * (float)hl - 1.f) * 0.5f;
  const float x0f = floorf(ix), y0f = floorf(iy);
  const float fx1 = ix - x0f, fy1 = iy - y0f;
  const float fx0 = 1.f - fx1, fy0 = 1.f - fy1;
  const int xi = (int)x0f, yi = (int)y0f;

  const float vx0 = ((unsigned)xi < (unsigned)wl) ? 1.f : 0.f;
  const float vx1 = ((unsigned)(xi + 1) < (unsigned)wl) ? 1.f : 0.f;
  const float vy0 = ((unsigned)yi < (unsigned)hl) ? 1.f : 0.f;
  const float vy1 = ((unsigned)(yi + 1) < (unsigned)hl) ? 1.f : 0.f;
  const int xc0 = min(max(xi, 0), wl - 1);
  const int xc1 = min(max(xi + 1, 0), wl - 1);
  const int yc0 = min(max(yi, 0), hl - 1);
  const int yc1 = min(max(yi + 1, 0), hl - 1);

  const unsigned short* base = Wx + (size_t)imgbase * 128 + (m * 16 + half * 8);
  const unsigned short* p00 = base + (size_t)(yc0 * wl + xc0) * 128;
  const unsigned short* p01 = base + (size_t)(yc0 * wl + xc1) * 128;
  const unsigned short* p10 = base + (size_t)(yc1 * wl + xc0) * 128;
  const unsigned short* p11 = base + (size_t)(yc1 * wl + xc1) * 128;

  // 4 independent 16B gathers, single clause
  const us8 g00 = *(const us8*)p00;
  const us8 g01 = *(const us8*)p01;
  const us8 g10 = *(const us8*)p10;
  const us8 g11 = *(const us8*)p11;

  // --- softmax on bf16 logits (overlaps gather latency) ---
  float lg[8];
#pragma unroll
  for (int s = 0; s < 8; ++s) lg[s] = bf2f(alv[s]);
  float mx = -3.0e38f;
#pragma unroll
  for (int s = 0; s < 8; ++s) mx = fmaxf(mx, lg[s]);
  float se = 0.f;
#pragma unroll
  for (int s = 0; s < 8; ++s) { lg[s] = __expf(lg[s] - mx); se += lg[s]; }
  const float inv = 1.f / se;

  const float w00 = fy0 * fx0 * vy0 * vx0;
  const float w01 = fy0 * fx1 * vy0 * vx1;
  const float w10 = fy1 * fx0 * vy1 * vx0;
  const float w11 = fy1 * fx1 * vy1 * vx1;

  float o = 0.f;
#pragma unroll
  for (int s = 0; s < 8; ++s) {
    float v = w00 * bf2f(g00[s]);
    v = fmaf(w01, bf2f(g01[s]), v);
    v = fmaf(w10, bf2f(g10[s]), v);
    v = fmaf(w11, bf2f(g11[s]), v);
    o = fmaf(lg[s] * inv, v, o);
  }
  Pbf[(size_t)q * 128 + t] = f2bf(o);
}

// ---------------------------------------------------------------------------
extern "C" void kernel_launch(void* const* d_in, const int* in_sizes, int n_in,
                              void* d_out, int out_size, void* d_ws, size_t ws_size,
                              hipStream_t stream)
{
  const float* z_q = (const float*)d_in[0];
  const float* x0  = (const float*)d_in[1];
  const float* x1  = (const float*)d_in[2];
  const float* p_q = (const float*)d_in[3];
  const float* Wq  = (const float*)d_in[4];
  const float* bq  = (const float*)d_in[5];
  const float* Wd  = (const float*)d_in[6];
  const float* bd  = (const float*)d_in[7];
  const float* Wa  = (const float*)d_in[8];
  const float* ba  = (const float*)d_in[9];
  const float* Wp  = (const float*)d_in[10];
  const float* bp  = (const float*)d_in[11];
  const float* Wm  = (const float*)d_in[12];
  const float* bm  = (const float*)d_in[13];

  float* ws = (float*)d_ws;
  const int NQ = CB * CH * CW;   // 32768

  // bf16 weight area (ushorts): WtDA 24576 | WtP 16384 | WtM 16384
  unsigned short* Wts  = (unsigned short*)ws;
  unsigned short* WtDA = Wts;
  unsigned short* WtP  = Wts + 24576;
  unsigned short* WtM  = Wts + 40960;
  float* bda = ws + 28672;                        // 192 composed bias

  float* dl2 = ws + 28864;                        // [NQ,128] fp32 folded coords
  unsigned short* AlogBf = (unsigned short*)(dl2 + 4194304);   // [NQ,64] bf16
  unsigned short* Wx  = (unsigned short*)(dl2 + 4194304 + 2097152);  // [40960,128]
  unsigned short* Pbf = Wx + 5242880;             // [NQ,128] bf16

  prep_all_kernel<<<449, 256, 0, stream>>>(Wq, bq, Wd, bd, Wa, ba, Wp, Wm,
                                           WtDA, WtP, WtM, bda);

  const int nZv = 1024;                           // 512 row-tiles x 2 col-halves
  pre_gemm_kernel<<<nZv + 1280, 256, 0, stream>>>(z_q, x0, x1, p_q, WtDA, bda,
                                                  WtP, bp, dl2, AlogBf, Wx, nZv);

  sample_attn_kernel<<<NQ, 128, 0, stream>>>(AlogBf, dl2, Wx, Pbf);

  final_gemm_kernel<<<NQ / 32, 256, 0, stream>>>(Pbf, WtM, bm, (float*)d_out);
}